// Round 1
// baseline (6915.118 us; speedup 1.0000x reference)
//
#include <hip/hip_runtime.h>
#include <hip/hip_bf16.h>
#include <math.h>

// ---------------- degree / norm ----------------

__global__ void deg_kernel(const int* __restrict__ src, const int* __restrict__ dst,
                           float* __restrict__ outdeg, float* __restrict__ indeg, int E) {
    int i = blockIdx.x * blockDim.x + threadIdx.x;
    if (i < E) {
        atomicAdd(&outdeg[src[i]], 1.0f);
        atomicAdd(&indeg[dst[i]], 1.0f);
    }
}

__global__ void norm_kernel(float* __restrict__ outdeg, float* __restrict__ indeg, int n) {
    int i = blockIdx.x * blockDim.x + threadIdx.x;
    if (i < n) {
        outdeg[i] = rsqrtf(fmaxf(outdeg[i], 1.0f));
        indeg[i]  = rsqrtf(fmaxf(indeg[i], 1.0f));
    }
}

// ---------------- GEMM (128 -> 128) + out_norm scale ----------------
// 8 nodes per block, 128 threads; x rows staged in LDS, W streamed (L2-cached).

__global__ void gemm128_scale(const float* __restrict__ x, const float* __restrict__ W,
                              const float* __restrict__ outn, float* __restrict__ h, int n) {
    __shared__ float xs[8][128];
    int base = blockIdx.x * 8;
    int j = threadIdx.x;
#pragma unroll
    for (int m = 0; m < 8; ++m) {
        int node = base + m;
        xs[m][j] = (node < n) ? x[(size_t)node * 128 + j] : 0.0f;
    }
    __syncthreads();
    float acc[8] = {0.f,0.f,0.f,0.f,0.f,0.f,0.f,0.f};
    for (int k = 0; k < 128; ++k) {
        float w = W[k * 128 + j];
#pragma unroll
        for (int m = 0; m < 8; ++m) acc[m] += xs[m][k] * w;
    }
#pragma unroll
    for (int m = 0; m < 8; ++m) {
        int node = base + m;
        if (node < n) h[(size_t)node * 128 + j] = acc[m] * outn[node];
    }
}

// ---------------- GEMM (128 -> 40) + out_norm scale ----------------

__global__ void gemm40_scale(const float* __restrict__ x, const float* __restrict__ W,
                             const float* __restrict__ outn, float* __restrict__ h, int n) {
    int idx = blockIdx.x * blockDim.x + threadIdx.x;
    if (idx >= n * 40) return;
    int node = idx / 40;
    int j = idx - node * 40;
    const float* xr = x + (size_t)node * 128;
    float acc = 0.0f;
#pragma unroll
    for (int k = 0; k < 128; ++k) acc += xr[k] * W[k * 40 + j];
    h[idx] = acc * outn[node];
}

// ---------------- edge scatter: agg[dst] += h[src] ----------------
// CH = D/4 float4 chunks per edge; consecutive threads cover one edge's chunks.

template <int CH>
__global__ void scatter_add(const float* __restrict__ h, const int* __restrict__ src,
                            const int* __restrict__ dst, float* __restrict__ agg,
                            long total, int D) {
    long i = (long)blockIdx.x * blockDim.x + threadIdx.x;
    if (i >= total) return;
    int e = (int)(i / CH);
    int c = (int)(i % CH);
    int s = src[e];
    int d = dst[e];
    const float4 v = *reinterpret_cast<const float4*>(h + (size_t)s * D + c * 4);
    float* a = agg + (size_t)d * D + c * 4;
    atomicAdd(a + 0, v.x);
    atomicAdd(a + 1, v.y);
    atomicAdd(a + 2, v.z);
    atomicAdd(a + 3, v.w);
}

// ---------------- epilogue: relu(agg * in_norm + b), D=128 ----------------

__global__ void finish_relu128(float* __restrict__ agg, const float* __restrict__ inn,
                               const float* __restrict__ b, int n) {
    int i = blockIdx.x * blockDim.x + threadIdx.x;
    if (i < n * 128) {
        int node = i >> 7;
        int j = i & 127;
        float v = agg[i] * inn[node] + b[j];
        agg[i] = fmaxf(v, 0.0f);
    }
}

// ---------------- final: (agg*inn + b3) -> log_softmax over 40 ----------------
// one 64-lane wave per node, lanes 0..39 active.

__global__ void logsoftmax40(const float* __restrict__ agg, const float* __restrict__ inn,
                             const float* __restrict__ b, float* __restrict__ out, int n) {
    int gw = (blockIdx.x * blockDim.x + threadIdx.x) >> 6;
    int lane = threadIdx.x & 63;
    if (gw >= n) return;
    float v = -INFINITY;
    if (lane < 40) v = agg[(size_t)gw * 40 + lane] * inn[gw] + b[lane];
    float m = v;
#pragma unroll
    for (int o = 32; o; o >>= 1) m = fmaxf(m, __shfl_xor(m, o));
    float e = (lane < 40) ? expf(v - m) : 0.0f;
    float s = e;
#pragma unroll
    for (int o = 32; o; o >>= 1) s += __shfl_xor(s, o);
    if (lane < 40) out[(size_t)gw * 40 + lane] = v - m - logf(s);
}

// ---------------- launch ----------------

extern "C" void kernel_launch(void* const* d_in, const int* in_sizes, int n_in,
                              void* d_out, int out_size, void* d_ws, size_t ws_size,
                              hipStream_t stream) {
    const float* x  = (const float*)d_in[0];
    const int*   ei = (const int*)d_in[1];
    const float* W1 = (const float*)d_in[2];
    const float* b1 = (const float*)d_in[3];
    const float* W2 = (const float*)d_in[4];
    const float* b2 = (const float*)d_in[5];
    const float* W3 = (const float*)d_in[6];
    const float* b3 = (const float*)d_in[7];

    const int n = in_sizes[0] / 128;
    const int E = in_sizes[1] / 2;
    const int* src = ei;
    const int* dst = ei + E;

    float* ws   = (float*)d_ws;
    float* outn = ws;                       // n floats (deg -> rsqrt in place)
    float* inn  = ws + n;                   // n floats
    float* bufA = ws + 2 * (size_t)n;       // n*128 floats
    float* bufB = bufA + (size_t)n * 128;   // n*128 floats

    // degrees -> norms
    hipMemsetAsync(outn, 0, 2 * (size_t)n * sizeof(float), stream);
    deg_kernel<<<(E + 255) / 256, 256, 0, stream>>>(src, dst, outn, inn, E);
    norm_kernel<<<(n + 255) / 256, 256, 0, stream>>>(outn, inn, n);

    const long tot128 = (long)E * 32;
    const long tot40  = (long)E * 10;

    // ----- layer 1: x -> bufA (h*outn) -> bufB (agg) -> relu in place -----
    gemm128_scale<<<(n + 7) / 8, 128, 0, stream>>>(x, W1, outn, bufA, n);
    hipMemsetAsync(bufB, 0, (size_t)n * 128 * sizeof(float), stream);
    scatter_add<32><<<(tot128 + 255) / 256, 256, 0, stream>>>(bufA, src, dst, bufB, tot128, 128);
    finish_relu128<<<((n * 128) + 255) / 256, 256, 0, stream>>>(bufB, inn, b1, n);

    // ----- layer 2: bufB -> bufA -> bufB -> relu -----
    gemm128_scale<<<(n + 7) / 8, 128, 0, stream>>>(bufB, W2, outn, bufA, n);
    hipMemsetAsync(bufB, 0, (size_t)n * 128 * sizeof(float), stream);
    scatter_add<32><<<(tot128 + 255) / 256, 256, 0, stream>>>(bufA, src, dst, bufB, tot128, 128);
    finish_relu128<<<((n * 128) + 255) / 256, 256, 0, stream>>>(bufB, inn, b2, n);

    // ----- layer 3: bufB -> bufA (n*40) -> bufB (n*40) -> log_softmax -----
    gemm40_scale<<<((n * 40) + 255) / 256, 256, 0, stream>>>(bufB, W3, outn, bufA, n);
    hipMemsetAsync(bufB, 0, (size_t)n * 40 * sizeof(float), stream);
    scatter_add<10><<<(tot40 + 255) / 256, 256, 0, stream>>>(bufA, src, dst, bufB, tot40, 40);
    logsoftmax40<<<(n + 3) / 4, 256, 0, stream>>>(bufB, inn, b3, (float*)d_out, n);
}

// Round 2
// 1192.394 us; speedup vs baseline: 5.7994x; 5.7994x over previous
//
#include <hip/hip_runtime.h>
#include <hip/hip_bf16.h>
#include <math.h>

// ---------------- degree histogram (int) ----------------

__global__ void deg_int_kernel(const int* __restrict__ src, const int* __restrict__ dst,
                               int* __restrict__ cnt_out, int* __restrict__ cnt_in, int E) {
    int i = blockIdx.x * blockDim.x + threadIdx.x;
    if (i < E) {
        atomicAdd(&cnt_out[src[i]], 1);
        atomicAdd(&cnt_in[dst[i]], 1);
    }
}

// int counts -> rsqrt(max(cnt,1)) float, in place
__global__ void norm_kernel(int* __restrict__ cnt_out, int* __restrict__ cnt_in, int n) {
    int i = blockIdx.x * blockDim.x + threadIdx.x;
    if (i < n) {
        float o = (float)cnt_out[i];
        float d = (float)cnt_in[i];
        ((float*)cnt_out)[i] = rsqrtf(fmaxf(o, 1.0f));
        ((float*)cnt_in)[i]  = rsqrtf(fmaxf(d, 1.0f));
    }
}

// ---------------- single-block exclusive scan -> row_ptr ----------------

__global__ void scan_rowptr(const int* __restrict__ cnt, int* __restrict__ row_ptr, int n) {
    __shared__ int s[1024];
    __shared__ int carry;
    int tid = threadIdx.x;
    if (tid == 0) carry = 0;
    __syncthreads();
    for (int base = 0; base < n; base += 1024) {
        int i = base + tid;
        int v = (i < n) ? cnt[i] : 0;
        s[tid] = v;
        __syncthreads();
        for (int off = 1; off < 1024; off <<= 1) {
            int t = (tid >= off) ? s[tid - off] : 0;
            __syncthreads();
            s[tid] += t;
            __syncthreads();
        }
        int c = carry;
        if (i < n) row_ptr[i] = c + s[tid] - v;
        int tot = s[1023];
        __syncthreads();
        if (tid == 0) carry = c + tot;
        __syncthreads();
    }
    if (tid == 0) row_ptr[n] = carry;
}

// ---------------- CSR fill: esrc sorted by dst ----------------

__global__ void fill_csr(const int* __restrict__ src, const int* __restrict__ dst,
                         const int* __restrict__ row_ptr, int* __restrict__ cursor,
                         int* __restrict__ esrc, int E) {
    int i = blockIdx.x * blockDim.x + threadIdx.x;
    if (i < E) {
        int d = dst[i];
        int pos = row_ptr[d] + atomicAdd(&cursor[d], 1);
        esrc[pos] = src[i];
    }
}

// ---------------- GEMM (128 -> 128) + out_norm scale ----------------

__global__ void gemm128_scale(const float* __restrict__ x, const float* __restrict__ W,
                              const float* __restrict__ outn, float* __restrict__ h, int n) {
    __shared__ float xs[8][128];
    int base = blockIdx.x * 8;
    int j = threadIdx.x;
#pragma unroll
    for (int m = 0; m < 8; ++m) {
        int node = base + m;
        xs[m][j] = (node < n) ? x[(size_t)node * 128 + j] : 0.0f;
    }
    __syncthreads();
    float acc[8] = {0.f,0.f,0.f,0.f,0.f,0.f,0.f,0.f};
    for (int k = 0; k < 128; ++k) {
        float w = W[k * 128 + j];
#pragma unroll
        for (int m = 0; m < 8; ++m) acc[m] += xs[m][k] * w;
    }
#pragma unroll
    for (int m = 0; m < 8; ++m) {
        int node = base + m;
        if (node < n) h[(size_t)node * 128 + j] = acc[m] * outn[node];
    }
}

// ---------------- GEMM (128 -> 40) + out_norm scale ----------------

__global__ void gemm40_scale(const float* __restrict__ x, const float* __restrict__ W,
                             const float* __restrict__ outn, float* __restrict__ h, int n) {
    int idx = blockIdx.x * blockDim.x + threadIdx.x;
    if (idx >= n * 40) return;
    int node = idx / 40;
    int j = idx - node * 40;
    const float* xr = x + (size_t)node * 128;
    float acc = 0.0f;
#pragma unroll
    for (int k = 0; k < 128; ++k) acc += xr[k] * W[k * 40 + j];
    h[idx] = acc * outn[node];
}

// ---------------- CSR gather + relu(agg*inn + b), D=128 ----------------
// 2 nodes per 256-thread block; 128 threads per node (one feature each).

__global__ void gather128_relu(const float* __restrict__ h, const int* __restrict__ row_ptr,
                               const int* __restrict__ esrc, const float* __restrict__ inn,
                               const float* __restrict__ b, float* __restrict__ out, int n) {
    int node = blockIdx.x * 2 + (threadIdx.x >> 7);
    int j = threadIdx.x & 127;
    if (node >= n) return;
    int s0 = row_ptr[node], s1 = row_ptr[node + 1];
    float acc = 0.0f;
    int k = s0;
    for (; k + 1 < s1; k += 2) {
        int e0 = esrc[k], e1 = esrc[k + 1];
        float v0 = h[(size_t)e0 * 128 + j];
        float v1 = h[(size_t)e1 * 128 + j];
        acc += v0 + v1;
    }
    if (k < s1) acc += h[(size_t)esrc[k] * 128 + j];
    float v = acc * inn[node] + b[j];
    out[(size_t)node * 128 + j] = fmaxf(v, 0.0f);
}

// ---------------- CSR gather D=40 + in_norm + bias + log_softmax ----------------
// 4 nodes per 256-thread block; one 64-lane wave per node (lanes 0..39 active).

__global__ void gather40_lsm(const float* __restrict__ h, const int* __restrict__ row_ptr,
                             const int* __restrict__ esrc, const float* __restrict__ inn,
                             const float* __restrict__ b, float* __restrict__ out, int n) {
    int node = blockIdx.x * 4 + (threadIdx.x >> 6);
    int lane = threadIdx.x & 63;
    if (node >= n) return;
    int s0 = row_ptr[node], s1 = row_ptr[node + 1];
    float acc = 0.0f;
    if (lane < 40) {
        for (int k = s0; k < s1; ++k) acc += h[(size_t)esrc[k] * 40 + lane];
    }
    float v = (lane < 40) ? (acc * inn[node] + b[lane]) : -INFINITY;
    float m = v;
#pragma unroll
    for (int o = 32; o; o >>= 1) m = fmaxf(m, __shfl_xor(m, o));
    float e = (lane < 40) ? expf(v - m) : 0.0f;
    float s = e;
#pragma unroll
    for (int o = 32; o; o >>= 1) s += __shfl_xor(s, o);
    if (lane < 40) out[(size_t)node * 40 + lane] = v - m - logf(s);
}

// ---------------- launch ----------------

extern "C" void kernel_launch(void* const* d_in, const int* in_sizes, int n_in,
                              void* d_out, int out_size, void* d_ws, size_t ws_size,
                              hipStream_t stream) {
    const float* x  = (const float*)d_in[0];
    const int*   ei = (const int*)d_in[1];
    const float* W1 = (const float*)d_in[2];
    const float* b1 = (const float*)d_in[3];
    const float* W2 = (const float*)d_in[4];
    const float* b2 = (const float*)d_in[5];
    const float* W3 = (const float*)d_in[6];
    const float* b3 = (const float*)d_in[7];

    const int n = in_sizes[0] / 128;
    const int E = in_sizes[1] / 2;
    const int* src = ei;
    const int* dst = ei + E;

    // workspace layout (all 4-byte elements):
    // [outn n][inn n][row_ptr n+1][esrc E][bufA n*128][bufB n*128]
    float* ws      = (float*)d_ws;
    float* outn    = ws;                          // n (int counts, then float norm)
    float* inn     = outn + n;                    // n
    int*   row_ptr = (int*)(inn + n);             // n+1
    int*   esrc    = row_ptr + (n + 1);           // E
    float* bufA    = (float*)(esrc + E);          // n*128
    float* bufB    = bufA + (size_t)n * 128;      // n*128
    int*   cursor  = (int*)bufB;                  // n (transient, before bufB is used)

    // ----- build norms + CSR (once; shared by all 3 layers) -----
    hipMemsetAsync(outn, 0, 2 * (size_t)n * sizeof(float), stream);
    hipMemsetAsync(cursor, 0, (size_t)n * sizeof(int), stream);
    deg_int_kernel<<<(E + 255) / 256, 256, 0, stream>>>(src, dst, (int*)outn, (int*)inn, E);
    scan_rowptr<<<1, 1024, 0, stream>>>((int*)inn, row_ptr, n);
    norm_kernel<<<(n + 255) / 256, 256, 0, stream>>>((int*)outn, (int*)inn, n);
    fill_csr<<<(E + 255) / 256, 256, 0, stream>>>(src, dst, row_ptr, cursor, esrc, E);

    // ----- layer 1: x -> bufA (xW * outn) -> bufB (gather + relu) -----
    gemm128_scale<<<(n + 7) / 8, 128, 0, stream>>>(x, W1, outn, bufA, n);
    gather128_relu<<<(n + 1) / 2, 256, 0, stream>>>(bufA, row_ptr, esrc, inn, b1, bufB, n);

    // ----- layer 2: bufB -> bufA -> bufB -----
    gemm128_scale<<<(n + 7) / 8, 128, 0, stream>>>(bufB, W2, outn, bufA, n);
    gather128_relu<<<(n + 1) / 2, 256, 0, stream>>>(bufA, row_ptr, esrc, inn, b2, bufB, n);

    // ----- layer 3: bufB -> bufA (n*40) -> d_out (gather + log_softmax) -----
    gemm40_scale<<<((n * 40) + 255) / 256, 256, 0, stream>>>(bufB, W3, outn, bufA, n);
    gather40_lsm<<<(n + 3) / 4, 256, 0, stream>>>(bufA, row_ptr, esrc, inn, b3, (float*)d_out, n);
}

// Round 3
// 921.300 us; speedup vs baseline: 7.5058x; 1.2943x over previous
//
#include <hip/hip_runtime.h>
#include <hip/hip_bf16.h>
#include <math.h>

typedef __hip_bfloat16 bf16;

__device__ __forceinline__ float bflo(unsigned u) { return __uint_as_float(u << 16); }
__device__ __forceinline__ float bfhi(unsigned u) { return __uint_as_float(u & 0xffff0000u); }

// ---------------- degree histogram (int) ----------------

__global__ void deg_int_kernel(const int* __restrict__ src, const int* __restrict__ dst,
                               int* __restrict__ cnt_out, int* __restrict__ cnt_in, int E) {
    int i = blockIdx.x * blockDim.x + threadIdx.x;
    if (i < E) {
        atomicAdd(&cnt_out[src[i]], 1);
        atomicAdd(&cnt_in[dst[i]], 1);
    }
}

// int counts -> rsqrt(max(cnt,1)) float, in place
__global__ void norm_kernel(int* __restrict__ cnt_out, int* __restrict__ cnt_in, int n) {
    int i = blockIdx.x * blockDim.x + threadIdx.x;
    if (i < n) {
        float o = (float)cnt_out[i];
        float d = (float)cnt_in[i];
        ((float*)cnt_out)[i] = rsqrtf(fmaxf(o, 1.0f));
        ((float*)cnt_in)[i]  = rsqrtf(fmaxf(d, 1.0f));
    }
}

// ---------------- parallel exclusive scan (3 phases) ----------------

__global__ void scan_phaseA(const int* __restrict__ cnt, int* __restrict__ row_ptr,
                            int* __restrict__ bsum, int n) {
    __shared__ int s[1024];
    int tid = threadIdx.x;
    int gid = blockIdx.x * 1024 + tid;
    int v = (gid < n) ? cnt[gid] : 0;
    s[tid] = v;
    __syncthreads();
    for (int off = 1; off < 1024; off <<= 1) {
        int t = (tid >= off) ? s[tid - off] : 0;
        __syncthreads();
        s[tid] += t;
        __syncthreads();
    }
    if (gid < n) row_ptr[gid] = s[tid] - v;   // block-local exclusive
    if (tid == 1023) bsum[blockIdx.x] = s[1023];
}

__global__ void scan_phaseB(int* __restrict__ bsum, int nb) {
    __shared__ int s[1024];
    int tid = threadIdx.x;
    int v = (tid < nb) ? bsum[tid] : 0;
    s[tid] = v;
    __syncthreads();
    for (int off = 1; off < 1024; off <<= 1) {
        int t = (tid >= off) ? s[tid - off] : 0;
        __syncthreads();
        s[tid] += t;
        __syncthreads();
    }
    if (tid < nb) bsum[tid] = s[tid] - v;     // exclusive
}

__global__ void scan_phaseC(int* __restrict__ row_ptr, const int* __restrict__ bsum,
                            int n, int E) {
    int gid = blockIdx.x * blockDim.x + threadIdx.x;
    if (gid < n) row_ptr[gid] += bsum[gid >> 10];
    if (gid == 0) row_ptr[n] = E;
}

// ---------------- CSR fill: esrc sorted by dst ----------------

__global__ void fill_csr(const int* __restrict__ src, const int* __restrict__ dst,
                         const int* __restrict__ row_ptr, int* __restrict__ cursor,
                         int* __restrict__ esrc, int E) {
    int i = blockIdx.x * blockDim.x + threadIdx.x;
    if (i < E) {
        int d = dst[i];
        int pos = row_ptr[d] + atomicAdd(&cursor[d], 1);
        esrc[pos] = src[i];
    }
}

// ---------------- weight pack: Wp[k4*J + j].c = W[(k4*4+c)*J + j] ----------------

__global__ void pack_w(const float* __restrict__ W, float4* __restrict__ Wp, int J) {
    int idx = blockIdx.x * blockDim.x + threadIdx.x;
    if (idx >= J * 32) return;
    int k4 = idx / J;
    int j = idx - k4 * J;
    float4 v;
    v.x = W[(k4 * 4 + 0) * J + j];
    v.y = W[(k4 * 4 + 1) * J + j];
    v.z = W[(k4 * 4 + 2) * J + j];
    v.w = W[(k4 * 4 + 3) * J + j];
    Wp[idx] = v;
}

// ---------------- GEMM (128 -> 128) + out_norm scale -> bf16 ----------------
// 256 threads, 16 nodes per block. x tile in LDS; W packed (coalesced float4).

__global__ void gemm128_scale_bf(const float* __restrict__ x, const float4* __restrict__ Wp,
                                 const float* __restrict__ outn, bf16* __restrict__ h, int n) {
    __shared__ float xs[16][128];
    int base = blockIdx.x * 16;
    int tid = threadIdx.x;
    // stage 16 rows (512 float4) with 256 threads
    const float4* xv = (const float4*)(x + (size_t)base * 128);
    float4* xsv = (float4*)&xs[0][0];
    int limit4 = (n - base) * 32;
#pragma unroll
    for (int t = 0; t < 2; ++t) {
        int idx = tid + t * 256;
        float4 v = {0.f, 0.f, 0.f, 0.f};
        if (idx < limit4) v = xv[idx];
        xsv[idx] = v;
    }
    __syncthreads();
    int j = tid & 127;
    int mg = tid >> 7;  // 0/1 -> node subset
    float acc[8] = {0.f,0.f,0.f,0.f,0.f,0.f,0.f,0.f};
    for (int k4 = 0; k4 < 32; ++k4) {
        float4 w = Wp[k4 * 128 + j];
#pragma unroll
        for (int m = 0; m < 8; ++m) {
            float4 xr = *(const float4*)&xs[mg * 8 + m][k4 * 4];
            acc[m] += xr.x * w.x + xr.y * w.y + xr.z * w.z + xr.w * w.w;
        }
    }
#pragma unroll
    for (int m = 0; m < 8; ++m) {
        int node = base + mg * 8 + m;
        if (node < n) h[(size_t)node * 128 + j] = __float2bfloat16(acc[m] * outn[node]);
    }
}

// ---------------- GEMM (128 -> 40) + out_norm scale -> bf16 ----------------
// one 64-lane wave per node, lanes 0..39 active.

__global__ void gemm40_scale_bf(const float* __restrict__ x, const float4* __restrict__ Wp,
                                const float* __restrict__ outn, bf16* __restrict__ h, int n) {
    int node = blockIdx.x * 4 + (threadIdx.x >> 6);
    int j = threadIdx.x & 63;
    if (node >= n) return;
    const float4* xr = (const float4*)(x + (size_t)node * 128);
    float acc = 0.0f;
    if (j < 40) {
        for (int k4 = 0; k4 < 32; ++k4) {
            float4 xv = xr[k4];
            float4 w = Wp[k4 * 40 + j];
            acc += xv.x * w.x + xv.y * w.y + xv.z * w.z + xv.w * w.w;
        }
        h[(size_t)node * 40 + j] = __float2bfloat16(acc * outn[node]);
    }
}

// ---------------- CSR gather (bf16 rows) + relu(agg*inn + b) -> fp32 ----------------
// 64 lanes per node (2 features each, one u32 per edge); 4 nodes per 256-block.

__global__ void gather128_relu_bf(const bf16* __restrict__ h, const int* __restrict__ row_ptr,
                                  const int* __restrict__ esrc, const float* __restrict__ inn,
                                  const float* __restrict__ b, float* __restrict__ out, int n) {
    int node = blockIdx.x * 4 + (threadIdx.x >> 6);
    int lane = threadIdx.x & 63;
    if (node >= n) return;
    int s0 = row_ptr[node], s1 = row_ptr[node + 1];
    const unsigned* hu = (const unsigned*)h;
    float a0 = 0.f, a1 = 0.f, a2 = 0.f, a3 = 0.f;
    int k = s0;
    for (; k + 1 < s1; k += 2) {
        int e0 = esrc[k], e1 = esrc[k + 1];
        unsigned u0 = hu[(size_t)e0 * 64 + lane];
        unsigned u1 = hu[(size_t)e1 * 64 + lane];
        a0 += bflo(u0); a1 += bfhi(u0);
        a2 += bflo(u1); a3 += bfhi(u1);
    }
    if (k < s1) {
        unsigned u = hu[(size_t)esrc[k] * 64 + lane];
        a0 += bflo(u); a1 += bfhi(u);
    }
    float innv = inn[node];
    float2 bb = ((const float2*)b)[lane];
    float f0 = fmaxf((a0 + a2) * innv + bb.x, 0.0f);
    float f1 = fmaxf((a1 + a3) * innv + bb.y, 0.0f);
    ((float2*)out)[(size_t)node * 64 + lane] = make_float2(f0, f1);
}

// ---------------- CSR gather D=40 (bf16) + in_norm + bias + log_softmax ----------------

__global__ void gather40_lsm_bf(const bf16* __restrict__ h, const int* __restrict__ row_ptr,
                                const int* __restrict__ esrc, const float* __restrict__ inn,
                                const float* __restrict__ b, float* __restrict__ out, int n) {
    int node = blockIdx.x * 4 + (threadIdx.x >> 6);
    int lane = threadIdx.x & 63;
    if (node >= n) return;
    int s0 = row_ptr[node], s1 = row_ptr[node + 1];
    float acc = 0.0f;
    if (lane < 40) {
        for (int k = s0; k < s1; ++k)
            acc += __bfloat162float(h[(size_t)esrc[k] * 40 + lane]);
    }
    float v = (lane < 40) ? (acc * inn[node] + b[lane]) : -INFINITY;
    float m = v;
#pragma unroll
    for (int o = 32; o; o >>= 1) m = fmaxf(m, __shfl_xor(m, o));
    float e = (lane < 40) ? expf(v - m) : 0.0f;
    float s = e;
#pragma unroll
    for (int o = 32; o; o >>= 1) s += __shfl_xor(s, o);
    if (lane < 40) out[(size_t)node * 40 + lane] = v - m - logf(s);
}

// ---------------- launch ----------------

extern "C" void kernel_launch(void* const* d_in, const int* in_sizes, int n_in,
                              void* d_out, int out_size, void* d_ws, size_t ws_size,
                              hipStream_t stream) {
    const float* x  = (const float*)d_in[0];
    const int*   ei = (const int*)d_in[1];
    const float* W1 = (const float*)d_in[2];
    const float* b1 = (const float*)d_in[3];
    const float* W2 = (const float*)d_in[4];
    const float* b2 = (const float*)d_in[5];
    const float* W3 = (const float*)d_in[6];
    const float* b3 = (const float*)d_in[7];

    const int n = in_sizes[0] / 128;
    const int E = in_sizes[1] / 2;
    const int* src = ei;
    const int* dst = ei + E;
    const int nb = (n + 1023) / 1024;

    // workspace layout (4-byte units, 16B-aligned sections)
    char* wsb = (char*)d_ws;
    size_t off = 0;
    auto alloc = [&](size_t bytes) { void* p = wsb + off; off = (off + bytes + 63) & ~(size_t)63; return p; };
    int*    outn    = (int*)   alloc((size_t)n * 4);          // int deg -> float norm
    int*    inn     = (int*)   alloc((size_t)n * 4);
    int*    row_ptr = (int*)   alloc((size_t)(n + 1) * 4);
    int*    bsum    = (int*)   alloc(1024 * 4);
    int*    esrc    = (int*)   alloc((size_t)E * 4);
    float4* Wp1     = (float4*)alloc(128 * 32 * 16);
    float4* Wp2     = (float4*)alloc(128 * 32 * 16);
    float4* Wp3     = (float4*)alloc(40 * 32 * 16);
    float*  bufB    = (float*) alloc((size_t)n * 128 * 4);    // fp32 agg / gemm input
    bf16*   hbf     = (bf16*)  alloc((size_t)n * 128 * 2);    // bf16 gemm output
    int*    cursor  = (int*)bufB;                             // transient alias

    // ----- build norms + CSR (shared by all 3 layers) -----
    hipMemsetAsync(outn, 0, 2 * (size_t)n * sizeof(int), stream);
    hipMemsetAsync(cursor, 0, (size_t)n * sizeof(int), stream);
    deg_int_kernel<<<(E + 255) / 256, 256, 0, stream>>>(src, dst, outn, inn, E);
    scan_phaseA<<<nb, 1024, 0, stream>>>(inn, row_ptr, bsum, n);
    scan_phaseB<<<1, 1024, 0, stream>>>(bsum, nb);
    scan_phaseC<<<(n + 255) / 256, 256, 0, stream>>>(row_ptr, bsum, n, E);
    norm_kernel<<<(n + 255) / 256, 256, 0, stream>>>(outn, inn, n);
    fill_csr<<<(E + 255) / 256, 256, 0, stream>>>(src, dst, row_ptr, cursor, esrc, E);

    // ----- pack weights -----
    pack_w<<<(128 * 32 + 255) / 256, 256, 0, stream>>>(W1, Wp1, 128);
    pack_w<<<(128 * 32 + 255) / 256, 256, 0, stream>>>(W2, Wp2, 128);
    pack_w<<<(40 * 32 + 255) / 256, 256, 0, stream>>>(W3, Wp3, 40);

    float* outnf = (float*)outn;
    float* innf  = (float*)inn;

    // ----- layer 1: x -> hbf -> bufB -----
    gemm128_scale_bf<<<(n + 15) / 16, 256, 0, stream>>>(x, Wp1, outnf, hbf, n);
    gather128_relu_bf<<<(n + 3) / 4, 256, 0, stream>>>(hbf, row_ptr, esrc, innf, b1, bufB, n);

    // ----- layer 2: bufB -> hbf -> bufB -----
    gemm128_scale_bf<<<(n + 15) / 16, 256, 0, stream>>>(bufB, Wp2, outnf, hbf, n);
    gather128_relu_bf<<<(n + 3) / 4, 256, 0, stream>>>(hbf, row_ptr, esrc, innf, b2, bufB, n);

    // ----- layer 3: bufB -> hbf(40) -> d_out -----
    gemm40_scale_bf<<<(n + 3) / 4, 256, 0, stream>>>(bufB, Wp3, outnf, (bf16*)hbf, n);
    gather40_lsm_bf<<<(n + 3) / 4, 256, 0, stream>>>((bf16*)hbf, row_ptr, esrc, innf, b3,
                                                     (float*)d_out, n);
}

// Round 4
// 668.622 us; speedup vs baseline: 10.3423x; 1.3779x over previous
//
#include <hip/hip_runtime.h>
#include <hip/hip_bf16.h>
#include <math.h>

typedef __hip_bfloat16 bf16;
typedef __attribute__((ext_vector_type(8))) short short8v;  // 8 bf16 (4 VGPRs)
typedef __attribute__((ext_vector_type(4))) float f32x4;    // 4 fp32

__device__ __forceinline__ float bflo(unsigned u) { return __uint_as_float(u << 16); }
__device__ __forceinline__ float bfhi(unsigned u) { return __uint_as_float(u & 0xffff0000u); }
__device__ __forceinline__ unsigned short f2bf(float f) {   // round-to-nearest-even
    unsigned u = __float_as_uint(f);
    return (unsigned short)((u + 0x7fff + ((u >> 16) & 1)) >> 16);
}

// ---------------- degree histogram (int) ----------------

__global__ void deg_int_kernel(const int* __restrict__ src, const int* __restrict__ dst,
                               int* __restrict__ cnt_out, int* __restrict__ cnt_in, int E) {
    int i = blockIdx.x * blockDim.x + threadIdx.x;
    if (i < E) {
        atomicAdd(&cnt_out[src[i]], 1);
        atomicAdd(&cnt_in[dst[i]], 1);
    }
}

// int counts -> rsqrt(max(cnt,1)) float, in place
__global__ void norm_kernel(int* __restrict__ cnt_out, int* __restrict__ cnt_in, int n) {
    int i = blockIdx.x * blockDim.x + threadIdx.x;
    if (i < n) {
        float o = (float)cnt_out[i];
        float d = (float)cnt_in[i];
        ((float*)cnt_out)[i] = rsqrtf(fmaxf(o, 1.0f));
        ((float*)cnt_in)[i]  = rsqrtf(fmaxf(d, 1.0f));
    }
}

// ---------------- parallel exclusive scan (3 phases) ----------------

__global__ void scan_phaseA(const int* __restrict__ cnt, int* __restrict__ row_ptr,
                            int* __restrict__ bsum, int n) {
    __shared__ int s[1024];
    int tid = threadIdx.x;
    int gid = blockIdx.x * 1024 + tid;
    int v = (gid < n) ? cnt[gid] : 0;
    s[tid] = v;
    __syncthreads();
    for (int off = 1; off < 1024; off <<= 1) {
        int t = (tid >= off) ? s[tid - off] : 0;
        __syncthreads();
        s[tid] += t;
        __syncthreads();
    }
    if (gid < n) row_ptr[gid] = s[tid] - v;   // block-local exclusive
    if (tid == 1023) bsum[blockIdx.x] = s[1023];
}

__global__ void scan_phaseB(int* __restrict__ bsum, int nb) {
    __shared__ int s[1024];
    int tid = threadIdx.x;
    int v = (tid < nb) ? bsum[tid] : 0;
    s[tid] = v;
    __syncthreads();
    for (int off = 1; off < 1024; off <<= 1) {
        int t = (tid >= off) ? s[tid - off] : 0;
        __syncthreads();
        s[tid] += t;
        __syncthreads();
    }
    if (tid < nb) bsum[tid] = s[tid] - v;     // exclusive
}

__global__ void scan_phaseC(int* __restrict__ row_ptr, const int* __restrict__ bsum,
                            int n, int E) {
    int gid = blockIdx.x * blockDim.x + threadIdx.x;
    if (gid < n) row_ptr[gid] += bsum[gid >> 10];
    if (gid == 0) row_ptr[n] = E;
}

// ---------------- CSR fill: esrc sorted by dst ----------------

__global__ void fill_csr(const int* __restrict__ src, const int* __restrict__ dst,
                         const int* __restrict__ row_ptr, int* __restrict__ cursor,
                         int* __restrict__ esrc, int E) {
    int i = blockIdx.x * blockDim.x + threadIdx.x;
    if (i < E) {
        int d = dst[i];
        int pos = row_ptr[d] + atomicAdd(&cursor[d], 1);
        esrc[pos] = src[i];
    }
}

// ---------------- fp32 -> bf16 bulk convert (4 elems/thread) ----------------

__global__ void f32_to_bf16v(const float4* __restrict__ in, ushort4* __restrict__ out, long N4) {
    long i = (long)blockIdx.x * blockDim.x + threadIdx.x;
    if (i < N4) {
        float4 v = in[i];
        ushort4 o;
        o.x = f2bf(v.x); o.y = f2bf(v.y); o.z = f2bf(v.z); o.w = f2bf(v.w);
        out[i] = o;
    }
}

// ---------------- weight pack into B-fragment layout ----------------
// Wb[((sk)*NPAD + n)*8 + r] = W[(sk*8 + r)*NOUT + n], sk = s*4+kb in 0..15; pad n>=NOUT with 0.

__global__ void pack_wb(const float* __restrict__ W, bf16* __restrict__ Wb, int NOUT, int NPAD) {
    int idx = blockIdx.x * blockDim.x + threadIdx.x;
    int total = 16 * NPAD * 8;
    if (idx >= total) return;
    int r = idx & 7;
    int rest = idx >> 3;
    int nglob = rest % NPAD;
    int sk = rest / NPAD;
    int k = sk * 8 + r;
    float v = (nglob < NOUT) ? W[k * NOUT + nglob] : 0.0f;
    Wb[idx] = __float2bfloat16(v);
}

// ---------------- MFMA GEMM: H[n, NOUT] = bf16( (A[n,128] @ W) * outn[n] ) ----------------
// 256 threads = 4 waves; each wave computes a 16-row x NPAD tile via 16x16x32 bf16 MFMA.

template <int NT, int NOUT>
__global__ void gemm_mfma_bf(const bf16* __restrict__ A, const bf16* __restrict__ Wb,
                             const float* __restrict__ outn, bf16* __restrict__ H, int n) {
    constexpr int NPAD = NT * 16;
    int lane = threadIdx.x & 63;
    int wid = threadIdx.x >> 6;
    int base = (blockIdx.x * 4 + wid) * 16;
    if (base >= n) return;
    int m = lane & 15, kb = lane >> 4;
    int arow = base + m;

    short8v az = {0, 0, 0, 0, 0, 0, 0, 0};
    short8v a[4];
    const short8v* ap = (const short8v*)(A + (size_t)arow * 128);
#pragma unroll
    for (int s = 0; s < 4; ++s)
        a[s] = (arow < n) ? ap[s * 4 + kb] : az;   // frag slot (s*4+kb) = bf16 offset s*32+kb*8

    f32x4 zz = {0.f, 0.f, 0.f, 0.f};
    f32x4 acc[NT];
#pragma unroll
    for (int t = 0; t < NT; ++t) acc[t] = zz;

    const short8v* bp = (const short8v*)Wb;
#pragma unroll
    for (int s = 0; s < 4; ++s) {
#pragma unroll
        for (int t = 0; t < NT; ++t) {
            short8v b = bp[(size_t)(s * 4 + kb) * NPAD + t * 16 + m];
            acc[t] = __builtin_amdgcn_mfma_f32_16x16x32_bf16(a[s], b, acc[t], 0, 0, 0);
        }
    }

    int orow0 = base + kb * 4;   // C/D: col = lane&15, row = (lane>>4)*4 + reg
#pragma unroll
    for (int r = 0; r < 4; ++r) {
        int rr = orow0 + r;
        if (rr < n) {
            float sc = outn[rr];
#pragma unroll
            for (int t = 0; t < NT; ++t) {
                int col = t * 16 + m;
                if (col < NOUT)
                    H[(size_t)rr * NOUT + col] = __float2bfloat16(acc[t][r] * sc);
            }
        }
    }
}

// ---------------- CSR gather (bf16 rows) + relu(agg*inn + b) -> bf16 ----------------
// 64 lanes per node (2 features each); 4 nodes per 256-block.

__global__ void gather128_relu_bf(const bf16* __restrict__ h, const int* __restrict__ row_ptr,
                                  const int* __restrict__ esrc, const float* __restrict__ inn,
                                  const float* __restrict__ b, unsigned* __restrict__ out, int n) {
    int node = blockIdx.x * 4 + (threadIdx.x >> 6);
    int lane = threadIdx.x & 63;
    if (node >= n) return;
    int s0 = row_ptr[node], s1 = row_ptr[node + 1];
    const unsigned* hu = (const unsigned*)h;
    float a0 = 0.f, a1 = 0.f, a2 = 0.f, a3 = 0.f;
    int k = s0;
    for (; k + 1 < s1; k += 2) {
        int e0 = esrc[k], e1 = esrc[k + 1];
        unsigned u0 = hu[(size_t)e0 * 64 + lane];
        unsigned u1 = hu[(size_t)e1 * 64 + lane];
        a0 += bflo(u0); a1 += bfhi(u0);
        a2 += bflo(u1); a3 += bfhi(u1);
    }
    if (k < s1) {
        unsigned u = hu[(size_t)esrc[k] * 64 + lane];
        a0 += bflo(u); a1 += bfhi(u);
    }
    float innv = inn[node];
    float2 bb = ((const float2*)b)[lane];
    float f0 = fmaxf((a0 + a2) * innv + bb.x, 0.0f);
    float f1 = fmaxf((a1 + a3) * innv + bb.y, 0.0f);
    unsigned pk = (unsigned)f2bf(f0) | ((unsigned)f2bf(f1) << 16);
    out[(size_t)node * 64 + lane] = pk;
}

// ---------------- CSR gather D=40 (bf16) + in_norm + bias + log_softmax ----------------

__global__ void gather40_lsm_bf(const bf16* __restrict__ h, const int* __restrict__ row_ptr,
                                const int* __restrict__ esrc, const float* __restrict__ inn,
                                const float* __restrict__ b, float* __restrict__ out, int n) {
    int node = blockIdx.x * 4 + (threadIdx.x >> 6);
    int lane = threadIdx.x & 63;
    if (node >= n) return;
    int s0 = row_ptr[node], s1 = row_ptr[node + 1];
    float acc = 0.0f;
    if (lane < 40) {
        for (int k = s0; k < s1; ++k)
            acc += __bfloat162float(h[(size_t)esrc[k] * 40 + lane]);
    }
    float v = (lane < 40) ? (acc * inn[node] + b[lane]) : -INFINITY;
    float m = v;
#pragma unroll
    for (int o = 32; o; o >>= 1) m = fmaxf(m, __shfl_xor(m, o));
    float e = (lane < 40) ? expf(v - m) : 0.0f;
    float s = e;
#pragma unroll
    for (int o = 32; o; o >>= 1) s += __shfl_xor(s, o);
    if (lane < 40) out[(size_t)node * 40 + lane] = v - m - logf(s);
}

// ---------------- launch ----------------

extern "C" void kernel_launch(void* const* d_in, const int* in_sizes, int n_in,
                              void* d_out, int out_size, void* d_ws, size_t ws_size,
                              hipStream_t stream) {
    const float* x  = (const float*)d_in[0];
    const int*   ei = (const int*)d_in[1];
    const float* W1 = (const float*)d_in[2];
    const float* b1 = (const float*)d_in[3];
    const float* W2 = (const float*)d_in[4];
    const float* b2 = (const float*)d_in[5];
    const float* W3 = (const float*)d_in[6];
    const float* b3 = (const float*)d_in[7];

    const int n = in_sizes[0] / 128;
    const int E = in_sizes[1] / 2;
    const int* src = ei;
    const int* dst = ei + E;
    const int nb = (n + 1023) / 1024;

    // workspace layout
    char* wsb = (char*)d_ws;
    size_t off = 0;
    auto alloc = [&](size_t bytes) { void* p = wsb + off; off = (off + bytes + 63) & ~(size_t)63; return p; };
    int*  outn    = (int*)alloc((size_t)n * 4);           // int deg -> float norm
    int*  inn     = (int*)alloc((size_t)n * 4);
    int*  row_ptr = (int*)alloc((size_t)(n + 1) * 4);
    int*  bsum    = (int*)alloc(1024 * 4);
    int*  esrc    = (int*)alloc((size_t)E * 4);
    bf16* Wb1     = (bf16*)alloc(16 * 128 * 8 * 2);       // 32 KB
    bf16* Wb2     = (bf16*)alloc(16 * 128 * 8 * 2);
    bf16* Wb3     = (bf16*)alloc(16 * 48 * 8 * 2);        // padded to 48
    bf16* xb      = (bf16*)alloc((size_t)n * 128 * 2);    // bf16 x
    bf16* hb      = (bf16*)alloc((size_t)n * 128 * 2);    // gemm output
    bf16* gb      = (bf16*)alloc((size_t)n * 128 * 2);    // gather output
    int*  cursor  = (int*)gb;                             // transient (before gb's first use)

    // ----- build norms + CSR (shared by all 3 layers) -----
    hipMemsetAsync(outn, 0, 2 * (size_t)n * sizeof(int), stream);
    hipMemsetAsync(cursor, 0, (size_t)n * sizeof(int), stream);
    deg_int_kernel<<<(E + 255) / 256, 256, 0, stream>>>(src, dst, outn, inn, E);
    scan_phaseA<<<nb, 1024, 0, stream>>>(inn, row_ptr, bsum, n);
    scan_phaseB<<<1, 1024, 0, stream>>>(bsum, nb);
    scan_phaseC<<<(n + 255) / 256, 256, 0, stream>>>(row_ptr, bsum, n, E);
    norm_kernel<<<(n + 255) / 256, 256, 0, stream>>>(outn, inn, n);
    fill_csr<<<(E + 255) / 256, 256, 0, stream>>>(src, dst, row_ptr, cursor, esrc, E);

    // ----- pack weights + convert x -----
    pack_wb<<<(16 * 128 * 8 + 255) / 256, 256, 0, stream>>>(W1, Wb1, 128, 128);
    pack_wb<<<(16 * 128 * 8 + 255) / 256, 256, 0, stream>>>(W2, Wb2, 128, 128);
    pack_wb<<<(16 * 48 * 8 + 255) / 256, 256, 0, stream>>>(W3, Wb3, 40, 48);
    long N4 = (long)n * 32;
    f32_to_bf16v<<<(N4 + 255) / 256, 256, 0, stream>>>((const float4*)x, (ushort4*)xb, N4);

    float* outnf = (float*)outn;
    float* innf  = (float*)inn;
    const int gblk = (n + 63) / 64;

    // ----- layer 1: xb -> hb -> gb -----
    gemm_mfma_bf<8, 128><<<gblk, 256, 0, stream>>>(xb, Wb1, outnf, hb, n);
    gather128_relu_bf<<<(n + 3) / 4, 256, 0, stream>>>(hb, row_ptr, esrc, innf, b1, (unsigned*)gb, n);

    // ----- layer 2: gb -> hb -> gb -----
    gemm_mfma_bf<8, 128><<<gblk, 256, 0, stream>>>(gb, Wb2, outnf, hb, n);
    gather128_relu_bf<<<(n + 3) / 4, 256, 0, stream>>>(hb, row_ptr, esrc, innf, b2, (unsigned*)gb, n);

    // ----- layer 3: gb -> hb(n*40) -> d_out -----
    gemm_mfma_bf<3, 40><<<gblk, 256, 0, stream>>>(gb, Wb3, outnf, hb, n);
    gather40_lsm_bf<<<(n + 3) / 4, 256, 0, stream>>>(hb, row_ptr, esrc, innf, b3, (float*)d_out, n);
}

// Round 5
// 534.499 us; speedup vs baseline: 12.9376x; 1.2509x over previous
//
#include <hip/hip_runtime.h>
#include <hip/hip_bf16.h>
#include <math.h>

typedef __hip_bfloat16 bf16;
typedef __attribute__((ext_vector_type(8))) short short8v;  // 8 bf16 (4 VGPRs)
typedef __attribute__((ext_vector_type(4))) float f32x4;    // 4 fp32

__device__ __forceinline__ float bflo(unsigned u) { return __uint_as_float(u << 16); }
__device__ __forceinline__ float bfhi(unsigned u) { return __uint_as_float(u & 0xffff0000u); }
__device__ __forceinline__ unsigned short f2bf(float f) {   // round-to-nearest-even
    unsigned u = __float_as_uint(f);
    return (unsigned short)((u + 0x7fff + ((u >> 16) & 1)) >> 16);
}

// ---------------- degree histogram (int) ----------------

__global__ void deg_int_kernel(const int* __restrict__ src, const int* __restrict__ dst,
                               int* __restrict__ cnt_out, int* __restrict__ cnt_in, int E) {
    int i = blockIdx.x * blockDim.x + threadIdx.x;
    if (i < E) {
        atomicAdd(&cnt_out[src[i]], 1);
        atomicAdd(&cnt_in[dst[i]], 1);
    }
}

// int counts -> rsqrt(max(cnt,1)) float, in place
__global__ void norm_kernel(int* __restrict__ cnt_out, int* __restrict__ cnt_in, int n) {
    int i = blockIdx.x * blockDim.x + threadIdx.x;
    if (i < n) {
        float o = (float)cnt_out[i];
        float d = (float)cnt_in[i];
        ((float*)cnt_out)[i] = rsqrtf(fmaxf(o, 1.0f));
        ((float*)cnt_in)[i]  = rsqrtf(fmaxf(d, 1.0f));
    }
}

// ---------------- parallel exclusive scan (3 phases) ----------------

__global__ void scan_phaseA(const int* __restrict__ cnt, int* __restrict__ row_ptr,
                            int* __restrict__ bsum, int n) {
    __shared__ int s[1024];
    int tid = threadIdx.x;
    int gid = blockIdx.x * 1024 + tid;
    int v = (gid < n) ? cnt[gid] : 0;
    s[tid] = v;
    __syncthreads();
    for (int off = 1; off < 1024; off <<= 1) {
        int t = (tid >= off) ? s[tid - off] : 0;
        __syncthreads();
        s[tid] += t;
        __syncthreads();
    }
    if (gid < n) row_ptr[gid] = s[tid] - v;   // block-local exclusive
    if (tid == 1023) bsum[blockIdx.x] = s[1023];
}

__global__ void scan_phaseB(int* __restrict__ bsum, int nb) {
    __shared__ int s[1024];
    int tid = threadIdx.x;
    int v = (tid < nb) ? bsum[tid] : 0;
    s[tid] = v;
    __syncthreads();
    for (int off = 1; off < 1024; off <<= 1) {
        int t = (tid >= off) ? s[tid - off] : 0;
        __syncthreads();
        s[tid] += t;
        __syncthreads();
    }
    if (tid < nb) bsum[tid] = s[tid] - v;     // exclusive
}

__global__ void scan_phaseC(int* __restrict__ row_ptr, const int* __restrict__ bsum,
                            int n, int E) {
    int gid = blockIdx.x * blockDim.x + threadIdx.x;
    if (gid < n) row_ptr[gid] += bsum[gid >> 10];
    if (gid == 0) row_ptr[n] = E;
}

// ---------------- CSR fill: esrc sorted by dst ----------------

__global__ void fill_csr(const int* __restrict__ src, const int* __restrict__ dst,
                         const int* __restrict__ row_ptr, int* __restrict__ cursor,
                         int* __restrict__ esrc, int E) {
    int i = blockIdx.x * blockDim.x + threadIdx.x;
    if (i < E) {
        int d = dst[i];
        int pos = row_ptr[d] + atomicAdd(&cursor[d], 1);
        esrc[pos] = src[i];
    }
}

// ---------------- weight pack into B-fragment layout ----------------
// Wb[((sk)*NPAD + n)*8 + r] = W[(sk*8 + r)*NOUT + n], sk in 0..15; pad n>=NOUT with 0.

__global__ void pack_wb(const float* __restrict__ W, bf16* __restrict__ Wb, int NOUT, int NPAD) {
    int idx = blockIdx.x * blockDim.x + threadIdx.x;
    int total = 16 * NPAD * 8;
    if (idx >= total) return;
    int r = idx & 7;
    int rest = idx >> 3;
    int nglob = rest % NPAD;
    int sk = rest / NPAD;
    int k = sk * 8 + r;
    float v = (nglob < NOUT) ? W[k * NOUT + nglob] : 0.0f;
    Wb[idx] = __float2bfloat16(v);
}

// ---------------- MFMA GEMM: H[n, NPAD] = bf16( (A[n,128] @ Wpad) * outn[n] ) ----------------
// 256 threads = 4 waves; each wave computes a 16-row x NPAD tile via 16x16x32 bf16 MFMA.
// AF32: A is fp32 (converted in-register); else A is bf16. Padded cols are exact zeros.

template <int NT, bool AF32>
__global__ void gemm_mfma_bf(const bf16* __restrict__ A, const float* __restrict__ Af,
                             const bf16* __restrict__ Wb, const float* __restrict__ outn,
                             bf16* __restrict__ H, int n) {
    constexpr int NPAD = NT * 16;
    int lane = threadIdx.x & 63;
    int wid = threadIdx.x >> 6;
    int base = (blockIdx.x * 4 + wid) * 16;
    if (base >= n) return;
    int m = lane & 15, kb = lane >> 4;
    int arow = base + m;

    short8v az = {0, 0, 0, 0, 0, 0, 0, 0};
    short8v a[4];
    if constexpr (AF32) {
        const float4* apf = (const float4*)(Af + (size_t)arow * 128);
#pragma unroll
        for (int s = 0; s < 4; ++s) {
            short8v w = az;
            if (arow < n) {
                float4 p = apf[s * 8 + kb * 2];
                float4 q = apf[s * 8 + kb * 2 + 1];
                w[0] = (short)f2bf(p.x); w[1] = (short)f2bf(p.y);
                w[2] = (short)f2bf(p.z); w[3] = (short)f2bf(p.w);
                w[4] = (short)f2bf(q.x); w[5] = (short)f2bf(q.y);
                w[6] = (short)f2bf(q.z); w[7] = (short)f2bf(q.w);
            }
            a[s] = w;
        }
    } else {
        const short8v* ap = (const short8v*)(A + (size_t)arow * 128);
#pragma unroll
        for (int s = 0; s < 4; ++s)
            a[s] = (arow < n) ? ap[s * 4 + kb] : az;
    }

    f32x4 zz = {0.f, 0.f, 0.f, 0.f};
    f32x4 acc[NT];
#pragma unroll
    for (int t = 0; t < NT; ++t) acc[t] = zz;

    const short8v* bp = (const short8v*)Wb;
#pragma unroll
    for (int s = 0; s < 4; ++s) {
#pragma unroll
        for (int t = 0; t < NT; ++t) {
            short8v b = bp[(size_t)(s * 4 + kb) * NPAD + t * 16 + m];
            acc[t] = __builtin_amdgcn_mfma_f32_16x16x32_bf16(a[s], b, acc[t], 0, 0, 0);
        }
    }

    int orow0 = base + kb * 4;   // C/D: col = lane&15, row = (lane>>4)*4 + reg
#pragma unroll
    for (int r = 0; r < 4; ++r) {
        int rr = orow0 + r;
        if (rr < n) {
            float sc = outn[rr];
#pragma unroll
            for (int t = 0; t < NT; ++t)
                H[(size_t)rr * NPAD + t * 16 + m] = __float2bfloat16(acc[t][r] * sc);
        }
    }
}

// ---------------- CSR gather (bf16 rows, stride 128) + relu(agg*inn + b) -> bf16 ----------------
// 64 lanes per node (2 features each); 4 nodes per 256-block; 4 edges in flight.

__global__ void gather128_relu_bf(const bf16* __restrict__ h, const int* __restrict__ row_ptr,
                                  const int* __restrict__ esrc, const float* __restrict__ inn,
                                  const float* __restrict__ b, unsigned* __restrict__ out, int n) {
    int node = blockIdx.x * 4 + (threadIdx.x >> 6);
    int lane = threadIdx.x & 63;
    if (node >= n) return;
    int s0 = row_ptr[node], s1 = row_ptr[node + 1];
    const unsigned* hu = (const unsigned*)h;
    float a0 = 0.f, a1 = 0.f, a2 = 0.f, a3 = 0.f;
    float a4 = 0.f, a5 = 0.f, a6 = 0.f, a7 = 0.f;
    int k = s0;
    for (; k + 3 < s1; k += 4) {
        int e0 = esrc[k], e1 = esrc[k + 1], e2 = esrc[k + 2], e3 = esrc[k + 3];
        unsigned u0 = hu[(size_t)e0 * 64 + lane];
        unsigned u1 = hu[(size_t)e1 * 64 + lane];
        unsigned u2 = hu[(size_t)e2 * 64 + lane];
        unsigned u3 = hu[(size_t)e3 * 64 + lane];
        a0 += bflo(u0); a1 += bfhi(u0);
        a2 += bflo(u1); a3 += bfhi(u1);
        a4 += bflo(u2); a5 += bfhi(u2);
        a6 += bflo(u3); a7 += bfhi(u3);
    }
    for (; k < s1; ++k) {
        unsigned u = hu[(size_t)esrc[k] * 64 + lane];
        a0 += bflo(u); a1 += bfhi(u);
    }
    float innv = inn[node];
    float2 bb = ((const float2*)b)[lane];
    float f0 = fmaxf(((a0 + a2) + (a4 + a6)) * innv + bb.x, 0.0f);
    float f1 = fmaxf(((a1 + a3) + (a5 + a7)) * innv + bb.y, 0.0f);
    unsigned pk = (unsigned)f2bf(f0) | ((unsigned)f2bf(f1) << 16);
    out[(size_t)node * 64 + lane] = pk;
}

// ---------------- CSR gather (bf16 rows, stride 64) + inn + bias + log_softmax ----------------
// one 64-lane wave per node: lanes 0..31 = even edges, 32..63 = odd edges;
// each lane holds one u32 (cols 2l, 2l+1 of 64-padded row). 2 edges/inst, unroll 2.

__global__ void gather40_lsm_p64(const bf16* __restrict__ h, const int* __restrict__ row_ptr,
                                 const int* __restrict__ esrc, const float* __restrict__ inn,
                                 const float* __restrict__ b, float* __restrict__ out, int n) {
    int node = blockIdx.x * 4 + (threadIdx.x >> 6);
    int lane = threadIdx.x & 63;
    if (node >= n) return;
    int s0 = row_ptr[node], s1 = row_ptr[node + 1];
    int grp = lane >> 5;        // which edge of the pair
    int l = lane & 31;          // u32 index within the 64-col row
    const unsigned* hu = (const unsigned*)h;   // row stride = 32 u32
    float a0 = 0.f, a1 = 0.f, a2 = 0.f, a3 = 0.f;
    int k = s0 + grp;
    for (; k + 2 < s1; k += 4) {
        int e0 = esrc[k], e1 = esrc[k + 2];
        unsigned u0 = hu[(size_t)e0 * 32 + l];
        unsigned u1 = hu[(size_t)e1 * 32 + l];
        a0 += bflo(u0); a1 += bfhi(u0);
        a2 += bflo(u1); a3 += bfhi(u1);
    }
    if (k < s1) {
        unsigned u = hu[(size_t)esrc[k] * 32 + l];
        a0 += bflo(u); a1 += bfhi(u);
    }
    a0 += a2; a1 += a3;
    // merge the two edge-groups (lane ±32)
    a0 += __shfl_xor(a0, 32);
    a1 += __shfl_xor(a1, 32);
    // log-softmax over 40 cols held as lanes 0..19 x 2 (duplicated in high half)
    float innv = inn[node];
    bool act = (l < 20);
    float2 bb = act ? ((const float2*)b)[l] : make_float2(0.f, 0.f);
    float v0 = act ? (a0 * innv + bb.x) : -INFINITY;
    float v1 = act ? (a1 * innv + bb.y) : -INFINITY;
    float m = fmaxf(v0, v1);
#pragma unroll
    for (int o = 16; o; o >>= 1) m = fmaxf(m, __shfl_xor(m, o));
    float e = act ? (expf(v0 - m) + expf(v1 - m)) : 0.0f;
#pragma unroll
    for (int o = 16; o; o >>= 1) e += __shfl_xor(e, o);
    float ls = m + logf(e);
    if (act && grp == 0)
        ((float2*)(out + (size_t)node * 40))[l] = make_float2(v0 - ls, v1 - ls);
}

// ---------------- launch ----------------

extern "C" void kernel_launch(void* const* d_in, const int* in_sizes, int n_in,
                              void* d_out, int out_size, void* d_ws, size_t ws_size,
                              hipStream_t stream) {
    const float* x  = (const float*)d_in[0];
    const int*   ei = (const int*)d_in[1];
    const float* W1 = (const float*)d_in[2];
    const float* b1 = (const float*)d_in[3];
    const float* W2 = (const float*)d_in[4];
    const float* b2 = (const float*)d_in[5];
    const float* W3 = (const float*)d_in[6];
    const float* b3 = (const float*)d_in[7];

    const int n = in_sizes[0] / 128;
    const int E = in_sizes[1] / 2;
    const int* src = ei;
    const int* dst = ei + E;
    const int nb = (n + 1023) / 1024;

    // workspace layout
    char* wsb = (char*)d_ws;
    size_t off = 0;
    auto alloc = [&](size_t bytes) { void* p = wsb + off; off = (off + bytes + 63) & ~(size_t)63; return p; };
    int*  outn    = (int*)alloc((size_t)n * 4);           // int deg -> float norm
    int*  inn     = (int*)alloc((size_t)n * 4);
    int*  row_ptr = (int*)alloc((size_t)(n + 1) * 4);
    int*  bsum    = (int*)alloc(1024 * 4);
    int*  esrc    = (int*)alloc((size_t)E * 4);
    bf16* Wb1     = (bf16*)alloc(16 * 128 * 8 * 2);       // 32 KB
    bf16* Wb2     = (bf16*)alloc(16 * 128 * 8 * 2);
    bf16* Wb3     = (bf16*)alloc(16 * 64 * 8 * 2);        // padded to 64 cols
    bf16* hb      = (bf16*)alloc((size_t)n * 128 * 2);    // gemm output
    bf16* gb      = (bf16*)alloc((size_t)n * 128 * 2);    // gather output
    int*  cursor  = (int*)gb;                             // transient (before gb's first use)

    // ----- build norms + CSR (shared by all 3 layers) -----
    hipMemsetAsync(outn, 0, 2 * (size_t)n * sizeof(int), stream);
    hipMemsetAsync(cursor, 0, (size_t)n * sizeof(int), stream);
    deg_int_kernel<<<(E + 255) / 256, 256, 0, stream>>>(src, dst, outn, inn, E);
    scan_phaseA<<<nb, 1024, 0, stream>>>(inn, row_ptr, bsum, n);
    scan_phaseB<<<1, 1024, 0, stream>>>(bsum, nb);
    scan_phaseC<<<(n + 255) / 256, 256, 0, stream>>>(row_ptr, bsum, n, E);
    norm_kernel<<<(n + 255) / 256, 256, 0, stream>>>(outn, inn, n);
    fill_csr<<<(E + 255) / 256, 256, 0, stream>>>(src, dst, row_ptr, cursor, esrc, E);

    // ----- pack weights -----
    pack_wb<<<(16 * 128 * 8 + 255) / 256, 256, 0, stream>>>(W1, Wb1, 128, 128);
    pack_wb<<<(16 * 128 * 8 + 255) / 256, 256, 0, stream>>>(W2, Wb2, 128, 128);
    pack_wb<<<(16 * 64 * 8 + 255) / 256, 256, 0, stream>>>(W3, Wb3, 40, 64);

    float* outnf = (float*)outn;
    float* innf  = (float*)inn;
    const int gblk = (n + 63) / 64;

    // ----- layer 1: x(fp32) -> hb -> gb -----
    gemm_mfma_bf<8, true><<<gblk, 256, 0, stream>>>(nullptr, x, Wb1, outnf, hb, n);
    gather128_relu_bf<<<(n + 3) / 4, 256, 0, stream>>>(hb, row_ptr, esrc, innf, b1, (unsigned*)gb, n);

    // ----- layer 2: gb -> hb -> gb -----
    gemm_mfma_bf<8, false><<<gblk, 256, 0, stream>>>(gb, nullptr, Wb2, outnf, hb, n);
    gather128_relu_bf<<<(n + 3) / 4, 256, 0, stream>>>(hb, row_ptr, esrc, innf, b2, (unsigned*)gb, n);

    // ----- layer 3: gb -> hb(n*64, zero-padded cols 40..63) -> d_out -----
    gemm_mfma_bf<4, false><<<gblk, 256, 0, stream>>>(gb, nullptr, Wb3, outnf, hb, n);
    gather40_lsm_p64<<<(n + 3) / 4, 256, 0, stream>>>(hb, row_ptr, esrc, innf, b3, (float*)d_out, n);
}